// Round 1
// 1258.693 us; speedup vs baseline: 1.0735x; 1.0735x over previous
//
#include <hip/hip_runtime.h>
#include <hip/hip_bf16.h>

#define HID 128
#define SEQ 512
#define INS 14
#define BC 16
// K0 = 160 : [x(14) | 1 | pad->32 | h0(128)]   -> 5 k-steps of 32
// K1 = 256 : [h0(128) | h1(128)]               -> 8 k-steps of 32
// xh0 now holds ONLY the x tile [x(14)|1|pad->32]; layer 0 reads its h0
// operand from xh1's h0 region (h0 was stored twice before).
// X0STRIDE=40 shorts = 80B = 20 dwords -> col*20 mod 32 gives 2-way (free).
#define X0STRIDE 40
#define X1STRIDE 264  // 256 + 8 pad shorts
#define NFRAG0 10240          // 8 waves * 4 gates * 5 ksteps * 64 lanes
#define NFRAG1 16384          // 8 waves * 4 gates * 8 ksteps * 64 lanes
#define W1BASE (NFRAG0 * 8)   // short offset of W1 region in ws

typedef __attribute__((ext_vector_type(8))) short bs8;
typedef __attribute__((ext_vector_type(4))) float f4;

__device__ __forceinline__ short f2bf(float f) {
    union { float f; unsigned u; } a; a.f = f;
    unsigned u = a.u;
    u += 0x7fffu + ((u >> 16) & 1u);   // RNE
    return (short)(u >> 16);
}
__device__ __forceinline__ float bf2f(short s) {
    union { unsigned u; float f; } a;
    a.u = ((unsigned)(unsigned short)s) << 16;
    return a.f;
}
__device__ __forceinline__ float sigm(float x) {
    return __builtin_amdgcn_rcpf(1.f + __builtin_amdgcn_exp2f(x * -1.44269504f));
}
__device__ __forceinline__ float tanh_(float x) {
    return __builtin_fmaf(2.f, __builtin_amdgcn_rcpf(1.f + __builtin_amdgcn_exp2f(x * -2.88539008f)), -1.f);
}

// ---------------------------------------------------------------------------
// prep: swizzle weights into MFMA B-fragment order in ws (bf16 bits).
// Frag (wv,g,ks,lane) -> ws shorts [fragIdx*8 .. +8), fragIdx linear in
// ((wv*4+g)*KSTEPS+ks)*64+lane. Bias folded into k==14 column of W0.
// ---------------------------------------------------------------------------
__global__ void lstm_prep(
    const float* __restrict__ Wih0, const float* __restrict__ Whh0,
    const float* __restrict__ bih0, const float* __restrict__ bhh0,
    const float* __restrict__ Wih1, const float* __restrict__ Whh1,
    short* __restrict__ wsw)
{
    int f = blockIdx.x * 256 + threadIdx.x;
    if (f >= NFRAG0 + NFRAG1) return;
    if (f < NFRAG0) {
        int lane = f & 63, t = f >> 6;
        int ks = t % 5, gw = t / 5, g = gw & 3, wv = gw >> 2;
        int row = g * HID + wv * 16 + (lane & 15);
        int kbase = ks * 32 + (lane >> 4) * 8;
        for (int j = 0; j < 8; ++j) {
            int k = kbase + j;
            float v;
            if (k < INS)        v = Wih0[row * INS + k];
            else if (k == INS)  v = bih0[row] + bhh0[row];
            else if (k < 32)    v = 0.f;
            else                v = Whh0[row * HID + (k - 32)];
            wsw[f * 8 + j] = f2bf(v);
        }
    } else {
        int fl = f - NFRAG0;
        int lane = fl & 63, t = fl >> 6;
        int ks = t & 7, g = (t >> 3) & 3, wv = t >> 5;
        int row = g * HID + wv * 16 + (lane & 15);
        int kbase = ks * 32 + (lane >> 4) * 8;
        for (int j = 0; j < 8; ++j) {
            int k = kbase + j;
            float v = (k < HID) ? Wih1[row * HID + k] : Whh1[row * HID + (k - HID)];
            wsw[f * 8 + j] = f2bf(v);
        }
    }
}

// ---------------------------------------------------------------------------
// main: layer-1 software-pipelined by ONE timestep.
// Iteration t computes L1/CELL1 for time t-1 (inputs h0(t-1), h1(t-2)) and
// L0/CELL0 for time t (inputs x(t), h0(t-1)) -> both only need data written
// before the single loop-top barrier. Barriers/step: 2 -> 1; 8 independent
// MFMA acc chains per body; CELL1's transcendental chain overlaps L0 MFMAs.
// Body order L1 -> CELL1 -> L0 -> CELL0 keeps peak live-set near the old
// kernel's (52 weight frags = 208 regs are the fixed cost); the scheduler
// may hoist L0 into L1's shadow if registers allow.
// ---------------------------------------------------------------------------
__global__ __attribute__((amdgpu_flat_work_group_size(512, 512)))
__attribute__((amdgpu_waves_per_eu(2, 2))) void lstm_fused(
    const float* __restrict__ x,
    const float* __restrict__ Wfc,  const float* __restrict__ bfc,
    const float* __restrict__ bih1, const float* __restrict__ bhh1,
    const short* __restrict__ wsw,
    float* __restrict__ out)
{
    __shared__ __align__(16) short xh0[2][BC][X0STRIDE];
    __shared__ __align__(16) short xh1[2][BC][X1STRIDE];

    const int tid  = threadIdx.x;
    const int lane = tid & 63;
    const int wv   = tid >> 6;      // 0..7
    const int col  = lane & 15;
    const int quad = lane >> 4;
    const int u    = wv * 16 + col; // hidden unit owned by this lane
    const int b0   = blockIdx.x * BC;

    // ---- load persistent weight fragments: named SSA values only ----
    const short* wb0 = wsw + ((wv * 20) * 64 + lane) * 8;           // wv*4*5
    const short* wb1 = wsw + W1BASE + ((wv * 32) * 64 + lane) * 8;  // wv*4*8
#define DW0(g,ks) const bs8 w0_##g##_##ks = *(const bs8*)(wb0 + ((g)*5+(ks))*512);
#define DW1(g,ks) const bs8 w1_##g##_##ks = *(const bs8*)(wb1 + ((g)*8+(ks))*512);
    DW0(0,0) DW0(0,1) DW0(0,2) DW0(0,3) DW0(0,4)
    DW0(1,0) DW0(1,1) DW0(1,2) DW0(1,3) DW0(1,4)
    DW0(2,0) DW0(2,1) DW0(2,2) DW0(2,3) DW0(2,4)
    DW0(3,0) DW0(3,1) DW0(3,2) DW0(3,3) DW0(3,4)
    DW1(0,0) DW1(0,1) DW1(0,2) DW1(0,3) DW1(0,4) DW1(0,5) DW1(0,6) DW1(0,7)
    DW1(1,0) DW1(1,1) DW1(1,2) DW1(1,3) DW1(1,4) DW1(1,5) DW1(1,6) DW1(1,7)
    DW1(2,0) DW1(2,1) DW1(2,2) DW1(2,3) DW1(2,4) DW1(2,5) DW1(2,6) DW1(2,7)
    DW1(3,0) DW1(3,1) DW1(3,2) DW1(3,3) DW1(3,4) DW1(3,5) DW1(3,6) DW1(3,7)

    const float b1_0 = bih1[0 * HID + u] + bhh1[0 * HID + u];
    const float b1_1 = bih1[1 * HID + u] + bhh1[1 * HID + u];
    const float b1_2 = bih1[2 * HID + u] + bhh1[2 * HID + u];
    const float b1_3 = bih1[3 * HID + u] + bhh1[3 * HID + u];

    // ---- LDS init: zeros + constant-1 bias column ----
    for (int idx = tid; idx < 2 * BC * X0STRIDE; idx += 512) ((short*)xh0)[idx] = 0;
    for (int idx = tid; idx < 2 * BC * X1STRIDE; idx += 512) ((short*)xh1)[idx] = 0;
    __syncthreads();
    if (tid < 2 * BC) xh0[tid >> 4][tid & 15][INS] = (short)0x3f80;  // 1.0 bf16

    // ---- x(t) staging: one float per thread, prefetched one step ahead ----
    const bool xldr = (tid < BC * INS);          // 224 threads
    const int  xm = tid / INS;
    const int  xi = tid - xm * INS;
    const float* xp = xldr ? (x + ((size_t)(b0 + xm) * SEQ) * INS + xi) : x;
    float xv = xldr ? xp[0] : 0.f;

    float c0_0 = 0.f, c0_1 = 0.f, c0_2 = 0.f, c0_3 = 0.f;
    float c1_0 = 0.f, c1_1 = 0.f, c1_2 = 0.f, c1_3 = 0.f;
    const int aoff = quad * 8;

    // ---- layer-0 x-kstep (reads xh0) and h-ksteps (read xh1's h0 region) ----
#define L0X { const bs8 af = *(const bs8*)&xh0[p][col][aoff]; \
        acc0_0 = __builtin_amdgcn_mfma_f32_16x16x32_bf16(af, w0_0_0, acc0_0, 0,0,0); \
        acc0_1 = __builtin_amdgcn_mfma_f32_16x16x32_bf16(af, w0_1_0, acc0_1, 0,0,0); \
        acc0_2 = __builtin_amdgcn_mfma_f32_16x16x32_bf16(af, w0_2_0, acc0_2, 0,0,0); \
        acc0_3 = __builtin_amdgcn_mfma_f32_16x16x32_bf16(af, w0_3_0, acc0_3, 0,0,0); }
#define L0H(ks) { const bs8 af = *(const bs8*)&xh1[p][col][((ks)-1)*32 + aoff]; \
        acc0_0 = __builtin_amdgcn_mfma_f32_16x16x32_bf16(af, w0_0_##ks, acc0_0, 0,0,0); \
        acc0_1 = __builtin_amdgcn_mfma_f32_16x16x32_bf16(af, w0_1_##ks, acc0_1, 0,0,0); \
        acc0_2 = __builtin_amdgcn_mfma_f32_16x16x32_bf16(af, w0_2_##ks, acc0_2, 0,0,0); \
        acc0_3 = __builtin_amdgcn_mfma_f32_16x16x32_bf16(af, w0_3_##ks, acc0_3, 0,0,0); }
#define L1K(ks) { const bs8 af = *(const bs8*)&xh1[p][col][(ks)*32 + aoff]; \
        acc1_0 = __builtin_amdgcn_mfma_f32_16x16x32_bf16(af, w1_0_##ks, acc1_0, 0,0,0); \
        acc1_1 = __builtin_amdgcn_mfma_f32_16x16x32_bf16(af, w1_1_##ks, acc1_1, 0,0,0); \
        acc1_2 = __builtin_amdgcn_mfma_f32_16x16x32_bf16(af, w1_2_##ks, acc1_2, 0,0,0); \
        acc1_3 = __builtin_amdgcn_mfma_f32_16x16x32_bf16(af, w1_3_##ks, acc1_3, 0,0,0); }

    // CELL0: h0(t) written ONLY into xh1[q]'s h0 region (single store)
#define CELL0(r) { \
        float ig = sigm(acc0_0[r]); \
        float fg = sigm(acc0_1[r]); \
        float gg = tanh_(acc0_2[r]); \
        float og = sigm(acc0_3[r]); \
        c0_##r = __builtin_fmaf(fg, c0_##r, ig * gg); \
        float h = og * tanh_(c0_##r); \
        xh1[q][quad * 4 + r][u] = f2bf(h); }
#define CELL1(r) { \
        float ig = sigm(acc1_0[r]); \
        float fg = sigm(acc1_1[r]); \
        float gg = tanh_(acc1_2[r]); \
        float og = sigm(acc1_3[r]); \
        c1_##r = __builtin_fmaf(fg, c1_##r, ig * gg); \
        float h = og * tanh_(c1_##r); \
        xh1[q][quad * 4 + r][HID + u] = f2bf(h); }

    // ---- prologue t=0: layer 0 only (h0(-1)=0 from zero-init) ----
    {
        const int p = 0, q = 1;
        if (xldr) xh0[p][xm][xi] = f2bf(xv);
        float xnext = xldr ? xp[INS] : 0.f;
        __syncthreads();
        f4 acc0_0 = {0.f,0.f,0.f,0.f}, acc0_1 = {0.f,0.f,0.f,0.f};
        f4 acc0_2 = {0.f,0.f,0.f,0.f}, acc0_3 = {0.f,0.f,0.f,0.f};
        L0X L0H(1) L0H(2) L0H(3) L0H(4)
        CELL0(0) CELL0(1) CELL0(2) CELL0(3)
        xv = xnext;
    }

    // ---- steady state: iter t does L1/CELL1 for t-1 and L0/CELL0 for t ----
    for (int t = 1; t < SEQ; ++t) {
        const int p = t & 1, q = p ^ 1;
        if (xldr) xh0[p][xm][xi] = f2bf(xv);
        float xnext = (xldr && (t + 1 < SEQ)) ? xp[(t + 1) * INS] : 0.f;
        __syncthreads();  // x(t), h0(t-1), h1(t-2) all visible in parity p

        f4 acc1_0 = {b1_0, b1_0, b1_0, b1_0};
        f4 acc1_1 = {b1_1, b1_1, b1_1, b1_1};
        f4 acc1_2 = {b1_2, b1_2, b1_2, b1_2};
        f4 acc1_3 = {b1_3, b1_3, b1_3, b1_3};
        L1K(0) L1K(1) L1K(2) L1K(3) L1K(4) L1K(5) L1K(6) L1K(7)
        CELL1(0) CELL1(1) CELL1(2) CELL1(3)

        f4 acc0_0 = {0.f,0.f,0.f,0.f}, acc0_1 = {0.f,0.f,0.f,0.f};
        f4 acc0_2 = {0.f,0.f,0.f,0.f}, acc0_3 = {0.f,0.f,0.f,0.f};
        L0X L0H(1) L0H(2) L0H(3) L0H(4)
        CELL0(0) CELL0(1) CELL0(2) CELL0(3)

        xv = xnext;
    }

    // ---- epilogue: L1/CELL1 for t = SEQ-1 (SEQ even -> parity 0) ----
    {
        const int p = 0, q = 1;
        __syncthreads();
        f4 acc1_0 = {b1_0, b1_0, b1_0, b1_0};
        f4 acc1_1 = {b1_1, b1_1, b1_1, b1_1};
        f4 acc1_2 = {b1_2, b1_2, b1_2, b1_2};
        f4 acc1_3 = {b1_3, b1_3, b1_3, b1_3};
        L1K(0) L1K(1) L1K(2) L1K(3) L1K(4) L1K(5) L1K(6) L1K(7)
        CELL1(0) CELL1(1) CELL1(2) CELL1(3)
    }
    __syncthreads();

    // ---- final FC (128 -> 1) + sigmoid; h1(SEQ-1) lives in xh1[1][.][HID+..] ----
    if (tid < BC) {
        float s = bfc[0];
#pragma unroll 8
        for (int k2 = 0; k2 < HID; ++k2)
            s += bf2f(xh1[1][tid][HID + k2]) * Wfc[k2];
        out[b0 + tid] = sigm(s);
    }
}

extern "C" void kernel_launch(void* const* d_in, const int* in_sizes, int n_in,
                              void* d_out, int out_size, void* d_ws, size_t ws_size,
                              hipStream_t stream) {
    const float* x    = (const float*)d_in[0];
    const float* Wih0 = (const float*)d_in[1];
    const float* Whh0 = (const float*)d_in[2];
    const float* bih0 = (const float*)d_in[3];
    const float* bhh0 = (const float*)d_in[4];
    const float* Wih1 = (const float*)d_in[5];
    const float* Whh1 = (const float*)d_in[6];
    const float* bih1 = (const float*)d_in[7];
    const float* bhh1 = (const float*)d_in[8];
    const float* Wfc  = (const float*)d_in[9];
    const float* bfc  = (const float*)d_in[10];
    float* out = (float*)d_out;
    short* wsw = (short*)d_ws;   // 426 KB of bf16 fragment-ordered weights

    int nfrag = NFRAG0 + NFRAG1;
    lstm_prep<<<(nfrag + 255) / 256, 256, 0, stream>>>(Wih0, Whh0, bih0, bhh0,
                                                       Wih1, Whh1, wsw);
    dim3 grid(2048 / BC);   // 128 blocks, 1 per CU
    dim3 block(512);        // 8 waves; each wave owns 16 hidden units
    lstm_fused<<<grid, block, 0, stream>>>(x, Wfc, bfc, bih1, bhh1, wsw, out);
}

// Round 2
// 1078.295 us; speedup vs baseline: 1.2531x; 1.1673x over previous
//
#include <hip/hip_runtime.h>
#include <hip/hip_bf16.h>

#define HID 128
#define SEQ 512
#define INS 14
#define BC 16
// K0 = 160 : [x(14) | 1 | pad->32 | h0(128)]   -> 5 k-steps of 32
// K1 = 256 : [h0(128) | h1(128)]               -> 8 k-steps of 32
// xh0 holds ONLY the x tile [x(14)|1|pad->32]; layer 0 reads its h0
// operand from xh1's h0 region.
#define X0STRIDE 40
#define X1STRIDE 264  // 256 + 8 pad shorts
#define NFRAG0 10240          // 8 waves * 4 gates * 5 ksteps * 64 lanes
#define NFRAG1 16384          // 8 waves * 4 gates * 8 ksteps * 64 lanes
#define W1BASE (NFRAG0 * 8)   // short offset of W1 region in ws

typedef __attribute__((ext_vector_type(8))) short bs8;
typedef __attribute__((ext_vector_type(4))) float f4;

__device__ __forceinline__ short f2bf(float f) {
    union { float f; unsigned u; } a; a.f = f;
    unsigned u = a.u;
    u += 0x7fffu + ((u >> 16) & 1u);   // RNE
    return (short)(u >> 16);
}
__device__ __forceinline__ float bf2f(short s) {
    union { unsigned u; float f; } a;
    a.u = ((unsigned)(unsigned short)s) << 16;
    return a.f;
}
__device__ __forceinline__ float sigm(float x) {
    return __builtin_amdgcn_rcpf(1.f + __builtin_amdgcn_exp2f(x * -1.44269504f));
}
__device__ __forceinline__ float tanh_(float x) {
    return __builtin_fmaf(2.f, __builtin_amdgcn_rcpf(1.f + __builtin_amdgcn_exp2f(x * -2.88539008f)), -1.f);
}

// ---------------------------------------------------------------------------
// prep: swizzle weights into MFMA B-fragment order in ws (bf16 bits).
// Frag (wv,g,ks,lane) -> ws shorts [fragIdx*8 .. +8), fragIdx linear in
// ((wv*4+g)*KSTEPS+ks)*64+lane. Bias folded into k==14 column of W0.
// ---------------------------------------------------------------------------
__global__ void lstm_prep(
    const float* __restrict__ Wih0, const float* __restrict__ Whh0,
    const float* __restrict__ bih0, const float* __restrict__ bhh0,
    const float* __restrict__ Wih1, const float* __restrict__ Whh1,
    short* __restrict__ wsw)
{
    int f = blockIdx.x * 256 + threadIdx.x;
    if (f >= NFRAG0 + NFRAG1) return;
    if (f < NFRAG0) {
        int lane = f & 63, t = f >> 6;
        int ks = t % 5, gw = t / 5, g = gw & 3, wv = gw >> 2;
        int row = g * HID + wv * 16 + (lane & 15);
        int kbase = ks * 32 + (lane >> 4) * 8;
        for (int j = 0; j < 8; ++j) {
            int k = kbase + j;
            float v;
            if (k < INS)        v = Wih0[row * INS + k];
            else if (k == INS)  v = bih0[row] + bhh0[row];
            else if (k < 32)    v = 0.f;
            else                v = Whh0[row * HID + (k - 32)];
            wsw[f * 8 + j] = f2bf(v);
        }
    } else {
        int fl = f - NFRAG0;
        int lane = fl & 63, t = fl >> 6;
        int ks = t & 7, g = (t >> 3) & 3, wv = t >> 5;
        int row = g * HID + wv * 16 + (lane & 15);
        int kbase = ks * 32 + (lane >> 4) * 8;
        for (int j = 0; j < 8; ++j) {
            int k = kbase + j;
            float v = (k < HID) ? Wih1[row * HID + k] : Whh1[row * HID + (k - HID)];
            wsw[f * 8 + j] = f2bf(v);
        }
    }
}

// ---------------------------------------------------------------------------
// main: layer-1 software-pipelined by ONE timestep (1 barrier/step), with
// register-pressure fix: only 36 weight frags (L0 all + L1 ks0-3) stay in
// registers (144 regs); the 16 L1 ks4-7 frags (64 regs) live in per-wave
// LDS (128 KB) and are re-read each step via conflict-free ds_read_b128.
// Round-1 evidence: 52 resident frags (208 regs) + merged-body liveness
// overflowed the 256-reg (128V+128A) budget at waves_per_eu(2,2) ->
// per-step spill churn (WRITE_SIZE 4.4 -> 20.5 MB). New live set ~210 regs.
// The in-loop __syncthreads is a workgroup fence, so the wlds loads cannot
// be LICM-hoisted back into registers.
// ---------------------------------------------------------------------------
__global__ __attribute__((amdgpu_flat_work_group_size(512, 512)))
__attribute__((amdgpu_waves_per_eu(2, 2))) void lstm_fused(
    const float* __restrict__ x,
    const float* __restrict__ Wfc,  const float* __restrict__ bfc,
    const float* __restrict__ bih1, const float* __restrict__ bhh1,
    const short* __restrict__ wsw,
    float* __restrict__ out)
{
    __shared__ __align__(16) short xh0[2][BC][X0STRIDE];
    __shared__ __align__(16) short xh1[2][BC][X1STRIDE];
    // L1 ks4-7 weights: [wv][ks-4][gate][lane][8] -> 128 KB, per-wave private
    __shared__ __align__(16) short wlds[8][4][4][64][8];

    const int tid  = threadIdx.x;
    const int lane = tid & 63;
    const int wv   = tid >> 6;      // 0..7
    const int col  = lane & 15;
    const int quad = lane >> 4;
    const int u    = wv * 16 + col; // hidden unit owned by this lane
    const int b0   = blockIdx.x * BC;

    // ---- register-resident weight fragments: L0 all 20, L1 ks0-3 (16) ----
    const short* wb0 = wsw + ((wv * 20) * 64 + lane) * 8;           // wv*4*5
    const short* wb1 = wsw + W1BASE + ((wv * 32) * 64 + lane) * 8;  // wv*4*8
#define DW0(g,ks) const bs8 w0_##g##_##ks = *(const bs8*)(wb0 + ((g)*5+(ks))*512);
#define DW1(g,ks) const bs8 w1_##g##_##ks = *(const bs8*)(wb1 + ((g)*8+(ks))*512);
    DW0(0,0) DW0(0,1) DW0(0,2) DW0(0,3) DW0(0,4)
    DW0(1,0) DW0(1,1) DW0(1,2) DW0(1,3) DW0(1,4)
    DW0(2,0) DW0(2,1) DW0(2,2) DW0(2,3) DW0(2,4)
    DW0(3,0) DW0(3,1) DW0(3,2) DW0(3,3) DW0(3,4)
    DW1(0,0) DW1(0,1) DW1(0,2) DW1(0,3)
    DW1(1,0) DW1(1,1) DW1(1,2) DW1(1,3)
    DW1(2,0) DW1(2,1) DW1(2,2) DW1(2,3)
    DW1(3,0) DW1(3,1) DW1(3,2) DW1(3,3)

    const float b1_0 = bih1[0 * HID + u] + bhh1[0 * HID + u];
    const float b1_1 = bih1[1 * HID + u] + bhh1[1 * HID + u];
    const float b1_2 = bih1[2 * HID + u] + bhh1[2 * HID + u];
    const float b1_3 = bih1[3 * HID + u] + bhh1[3 * HID + u];

    // ---- LDS init: zeros + constant-1 bias column + L1 ks4-7 weight tiles ----
    for (int idx = tid; idx < 2 * BC * X0STRIDE; idx += 512) ((short*)xh0)[idx] = 0;
    for (int idx = tid; idx < 2 * BC * X1STRIDE; idx += 512) ((short*)xh1)[idx] = 0;
#pragma unroll
    for (int f = 0; f < 16; ++f) {
        int ksm4 = f >> 2, g = f & 3;
        *(bs8*)&wlds[wv][ksm4][g][lane][0] =
            *(const bs8*)(wsw + W1BASE +
                (((wv * 4 + g) * 8 + (ksm4 + 4)) * 64 + lane) * 8);
    }
    __syncthreads();
    if (tid < 2 * BC) xh0[tid >> 4][tid & 15][INS] = (short)0x3f80;  // 1.0 bf16

    // ---- x(t) staging: one float per thread, prefetched one step ahead ----
    const bool xldr = (tid < BC * INS);          // 224 threads
    const int  xm = tid / INS;
    const int  xi = tid - xm * INS;
    const float* xp = xldr ? (x + ((size_t)(b0 + xm) * SEQ) * INS + xi) : x;
    float xv = xldr ? xp[0] : 0.f;

    float c0_0 = 0.f, c0_1 = 0.f, c0_2 = 0.f, c0_3 = 0.f;
    float c1_0 = 0.f, c1_1 = 0.f, c1_2 = 0.f, c1_3 = 0.f;
    const int aoff = quad * 8;

    // ---- layer-0 x-kstep (reads xh0) and h-ksteps (read xh1's h0 region) ----
#define L0X { const bs8 af = *(const bs8*)&xh0[p][col][aoff]; \
        acc0_0 = __builtin_amdgcn_mfma_f32_16x16x32_bf16(af, w0_0_0, acc0_0, 0,0,0); \
        acc0_1 = __builtin_amdgcn_mfma_f32_16x16x32_bf16(af, w0_1_0, acc0_1, 0,0,0); \
        acc0_2 = __builtin_amdgcn_mfma_f32_16x16x32_bf16(af, w0_2_0, acc0_2, 0,0,0); \
        acc0_3 = __builtin_amdgcn_mfma_f32_16x16x32_bf16(af, w0_3_0, acc0_3, 0,0,0); }
#define L0H(ks) { const bs8 af = *(const bs8*)&xh1[p][col][((ks)-1)*32 + aoff]; \
        acc0_0 = __builtin_amdgcn_mfma_f32_16x16x32_bf16(af, w0_0_##ks, acc0_0, 0,0,0); \
        acc0_1 = __builtin_amdgcn_mfma_f32_16x16x32_bf16(af, w0_1_##ks, acc0_1, 0,0,0); \
        acc0_2 = __builtin_amdgcn_mfma_f32_16x16x32_bf16(af, w0_2_##ks, acc0_2, 0,0,0); \
        acc0_3 = __builtin_amdgcn_mfma_f32_16x16x32_bf16(af, w0_3_##ks, acc0_3, 0,0,0); }
// L1 ks0-3: register weights
#define L1KR(ks) { const bs8 af = *(const bs8*)&xh1[p][col][(ks)*32 + aoff]; \
        acc1_0 = __builtin_amdgcn_mfma_f32_16x16x32_bf16(af, w1_0_##ks, acc1_0, 0,0,0); \
        acc1_1 = __builtin_amdgcn_mfma_f32_16x16x32_bf16(af, w1_1_##ks, acc1_1, 0,0,0); \
        acc1_2 = __builtin_amdgcn_mfma_f32_16x16x32_bf16(af, w1_2_##ks, acc1_2, 0,0,0); \
        acc1_3 = __builtin_amdgcn_mfma_f32_16x16x32_bf16(af, w1_3_##ks, acc1_3, 0,0,0); }
// L1 ks4-7: LDS weights (per-wave private, lane-contiguous -> conflict-free)
#define L1KL(ks) { const bs8 af = *(const bs8*)&xh1[p][col][(ks)*32 + aoff]; \
        const bs8 u0 = *(const bs8*)&wlds[wv][(ks)-4][0][lane][0]; \
        const bs8 u1 = *(const bs8*)&wlds[wv][(ks)-4][1][lane][0]; \
        const bs8 u2 = *(const bs8*)&wlds[wv][(ks)-4][2][lane][0]; \
        const bs8 u3 = *(const bs8*)&wlds[wv][(ks)-4][3][lane][0]; \
        acc1_0 = __builtin_amdgcn_mfma_f32_16x16x32_bf16(af, u0, acc1_0, 0,0,0); \
        acc1_1 = __builtin_amdgcn_mfma_f32_16x16x32_bf16(af, u1, acc1_1, 0,0,0); \
        acc1_2 = __builtin_amdgcn_mfma_f32_16x16x32_bf16(af, u2, acc1_2, 0,0,0); \
        acc1_3 = __builtin_amdgcn_mfma_f32_16x16x32_bf16(af, u3, acc1_3, 0,0,0); }

    // CELL0: h0(t) written ONLY into xh1[q]'s h0 region (single store)
#define CELL0(r) { \
        float ig = sigm(acc0_0[r]); \
        float fg = sigm(acc0_1[r]); \
        float gg = tanh_(acc0_2[r]); \
        float og = sigm(acc0_3[r]); \
        c0_##r = __builtin_fmaf(fg, c0_##r, ig * gg); \
        float h = og * tanh_(c0_##r); \
        xh1[q][quad * 4 + r][u] = f2bf(h); }
#define CELL1(r) { \
        float ig = sigm(acc1_0[r]); \
        float fg = sigm(acc1_1[r]); \
        float gg = tanh_(acc1_2[r]); \
        float og = sigm(acc1_3[r]); \
        c1_##r = __builtin_fmaf(fg, c1_##r, ig * gg); \
        float h = og * tanh_(c1_##r); \
        xh1[q][quad * 4 + r][HID + u] = f2bf(h); }

    // ---- prologue t=0: layer 0 only (h0(-1)=0 from zero-init) ----
    {
        const int p = 0, q = 1;
        if (xldr) xh0[p][xm][xi] = f2bf(xv);
        float xnext = xldr ? xp[INS] : 0.f;
        __syncthreads();
        f4 acc0_0 = {0.f,0.f,0.f,0.f}, acc0_1 = {0.f,0.f,0.f,0.f};
        f4 acc0_2 = {0.f,0.f,0.f,0.f}, acc0_3 = {0.f,0.f,0.f,0.f};
        L0X L0H(1) L0H(2) L0H(3) L0H(4)
        CELL0(0) CELL0(1) CELL0(2) CELL0(3)
        xv = xnext;
    }

    // ---- steady state: iter t does L1/CELL1 for t-1 and L0/CELL0 for t ----
    for (int t = 1; t < SEQ; ++t) {
        const int p = t & 1, q = p ^ 1;
        if (xldr) xh0[p][xm][xi] = f2bf(xv);
        float xnext = (xldr && (t + 1 < SEQ)) ? xp[(t + 1) * INS] : 0.f;
        __syncthreads();  // x(t), h0(t-1), h1(t-2) all visible in parity p

        f4 acc1_0 = {b1_0, b1_0, b1_0, b1_0};
        f4 acc1_1 = {b1_1, b1_1, b1_1, b1_1};
        f4 acc1_2 = {b1_2, b1_2, b1_2, b1_2};
        f4 acc1_3 = {b1_3, b1_3, b1_3, b1_3};
        L1KR(0) L1KR(1) L1KR(2) L1KR(3)
        L1KL(4) L1KL(5) L1KL(6) L1KL(7)
        CELL1(0) CELL1(1) CELL1(2) CELL1(3)

        f4 acc0_0 = {0.f,0.f,0.f,0.f}, acc0_1 = {0.f,0.f,0.f,0.f};
        f4 acc0_2 = {0.f,0.f,0.f,0.f}, acc0_3 = {0.f,0.f,0.f,0.f};
        L0X L0H(1) L0H(2) L0H(3) L0H(4)
        CELL0(0) CELL0(1) CELL0(2) CELL0(3)

        xv = xnext;
    }

    // ---- epilogue: L1/CELL1 for t = SEQ-1 (SEQ even -> parity 0) ----
    {
        const int p = 0, q = 1;
        __syncthreads();
        f4 acc1_0 = {b1_0, b1_0, b1_0, b1_0};
        f4 acc1_1 = {b1_1, b1_1, b1_1, b1_1};
        f4 acc1_2 = {b1_2, b1_2, b1_2, b1_2};
        f4 acc1_3 = {b1_3, b1_3, b1_3, b1_3};
        L1KR(0) L1KR(1) L1KR(2) L1KR(3)
        L1KL(4) L1KL(5) L1KL(6) L1KL(7)
        CELL1(0) CELL1(1) CELL1(2) CELL1(3)
    }
    __syncthreads();

    // ---- final FC (128 -> 1) + sigmoid; h1(SEQ-1) lives in xh1[1][.][HID+..] ----
    if (tid < BC) {
        float s = bfc[0];
#pragma unroll 8
        for (int k2 = 0; k2 < HID; ++k2)
            s += bf2f(xh1[1][tid][HID + k2]) * Wfc[k2];
        out[b0 + tid] = sigm(s);
    }
}

extern "C" void kernel_launch(void* const* d_in, const int* in_sizes, int n_in,
                              void* d_out, int out_size, void* d_ws, size_t ws_size,
                              hipStream_t stream) {
    const float* x    = (const float*)d_in[0];
    const float* Wih0 = (const float*)d_in[1];
    const float* Whh0 = (const float*)d_in[2];
    const float* bih0 = (const float*)d_in[3];
    const float* bhh0 = (const float*)d_in[4];
    const float* Wih1 = (const float*)d_in[5];
    const float* Whh1 = (const float*)d_in[6];
    const float* bih1 = (const float*)d_in[7];
    const float* bhh1 = (const float*)d_in[8];
    const float* Wfc  = (const float*)d_in[9];
    const float* bfc  = (const float*)d_in[10];
    float* out = (float*)d_out;
    short* wsw = (short*)d_ws;   // 426 KB of bf16 fragment-ordered weights

    int nfrag = NFRAG0 + NFRAG1;
    lstm_prep<<<(nfrag + 255) / 256, 256, 0, stream>>>(Wih0, Whh0, bih0, bhh0,
                                                       Wih1, Whh1, wsw);
    dim3 grid(2048 / BC);   // 128 blocks, 1 per CU
    dim3 block(512);        // 8 waves; each wave owns 16 hidden units
    lstm_fused<<<grid, block, 0, stream>>>(x, Wfc, bfc, bih1, bhh1, wsw, out);
}

// Round 4
// 977.296 us; speedup vs baseline: 1.3826x; 1.1033x over previous
//
#include <hip/hip_runtime.h>
#include <hip/hip_bf16.h>

#define HID 128
#define SEQ 512
#define INS 14
#define BC 16
// K0 = 160 : [x(14) | 1 | pad->32 | h0(128)]   -> 5 k-steps of 32
// K1 = 256 : [h0(128) | h1(128)]               -> 8 k-steps of 32
// xh0 holds ONLY the x tile [x(14)|1|pad->32]; layer 0 reads its h0
// operand from xh1's h0 region.
#define X0STRIDE 40
#define X1STRIDE 264  // 256 + 8 pad shorts; row stride 132 dw = 4 mod 32 -> 2-way reads (free)
#define NFRAG0 10240          // 8 waves * 4 gates * 5 ksteps * 64 lanes
#define NFRAG1 16384          // 8 waves * 4 gates * 8 ksteps * 64 lanes
#define W1BASE (NFRAG0 * 8)   // short offset of W1 region in ws

typedef __attribute__((ext_vector_type(8))) short bs8;
typedef __attribute__((ext_vector_type(4))) float f4;

__device__ __forceinline__ short f2bf(float f) {
    union { float f; unsigned u; } a; a.f = f;
    unsigned u = a.u;
    u += 0x7fffu + ((u >> 16) & 1u);   // RNE
    return (short)(u >> 16);
}
__device__ __forceinline__ float bf2f(short s) {
    union { unsigned u; float f; } a;
    a.u = ((unsigned)(unsigned short)s) << 16;
    return a.f;
}
__device__ __forceinline__ float sigm(float x) {
    return __builtin_amdgcn_rcpf(1.f + __builtin_amdgcn_exp2f(x * -1.44269504f));
}

// ---------------------------------------------------------------------------
// prep: swizzle weights into MFMA B-fragment order in ws (bf16 bits).
// ---------------------------------------------------------------------------
__global__ void lstm_prep(
    const float* __restrict__ Wih0, const float* __restrict__ Whh0,
    const float* __restrict__ bih0, const float* __restrict__ bhh0,
    const float* __restrict__ Wih1, const float* __restrict__ Whh1,
    short* __restrict__ wsw)
{
    int f = blockIdx.x * 256 + threadIdx.x;
    if (f >= NFRAG0 + NFRAG1) return;
    if (f < NFRAG0) {
        int lane = f & 63, t = f >> 6;
        int ks = t % 5, gw = t / 5, g = gw & 3, wv = gw >> 2;
        int row = g * HID + wv * 16 + (lane & 15);
        int kbase = ks * 32 + (lane >> 4) * 8;
        for (int j = 0; j < 8; ++j) {
            int k = kbase + j;
            float v;
            if (k < INS)        v = Wih0[row * INS + k];
            else if (k == INS)  v = bih0[row] + bhh0[row];
            else if (k < 32)    v = 0.f;
            else                v = Whh0[row * HID + (k - 32)];
            wsw[f * 8 + j] = f2bf(v);
        }
    } else {
        int fl = f - NFRAG0;
        int lane = fl & 63, t = fl >> 6;
        int ks = t & 7, g = (t >> 3) & 3, wv = t >> 5;
        int row = g * HID + wv * 16 + (lane & 15);
        int kbase = ks * 32 + (lane >> 4) * 8;
        for (int j = 0; j < 8; ++j) {
            int k = kbase + j;
            float v = (k < HID) ? Wih1[row * HID + k] : Whh1[row * HID + (k - HID)];
            wsw[f * 8 + j] = f2bf(v);
        }
    }
}

// ---------------------------------------------------------------------------
// main. Round-3 changes on top of the pipelined/LDS-weight structure:
//  (a) A-row af0..af7 loaded ONCE per step into named temps; L0H(ks) reuses
//      L1's af(ks-1) (identical addresses the compiler could not CSE across
//      CELL1's xh1[q] stores) -> 13 ds_read_b128 -> 9 per wave per step.
//  (b) CELL1 hand-interleaved between L0 MFMA macros: trans pipe and matrix
//      pipe fed concurrently instead of phase-blocked lockstep.
//  (c) merged-denominator cell math: 5 exp2 + 2 rcp per cell-row (was 5+5).
//      c' = [c*Di*Dg + (1-eg)*Df] / (Df*Di*Dg); h = (1-ec) / (Dc*Do).
// Spill canary: WRITE_SIZE (must stay ~KB; 8 KB @ r2).
// ---------------------------------------------------------------------------
__global__ __attribute__((amdgpu_flat_work_group_size(512, 512)))
__attribute__((amdgpu_waves_per_eu(2, 2))) void lstm_fused(
    const float* __restrict__ x,
    const float* __restrict__ Wfc,  const float* __restrict__ bfc,
    const float* __restrict__ bih1, const float* __restrict__ bhh1,
    const short* __restrict__ wsw,
    float* __restrict__ out)
{
    __shared__ __align__(16) short xh0[2][BC][X0STRIDE];
    __shared__ __align__(16) short xh1[2][BC][X1STRIDE];
    // L1 ks4-7 weights: [wv][ks-4][gate][lane][8] -> 128 KB, per-wave private
    __shared__ __align__(16) short wlds[8][4][4][64][8];

    const int tid  = threadIdx.x;
    const int lane = tid & 63;
    const int wv   = tid >> 6;      // 0..7
    const int col  = lane & 15;
    const int quad = lane >> 4;
    const int u    = wv * 16 + col; // hidden unit owned by this lane
    const int b0   = blockIdx.x * BC;

    // ---- register-resident weight fragments: L0 all 20, L1 ks0-3 (16) ----
    const short* wb0 = wsw + ((wv * 20) * 64 + lane) * 8;           // wv*4*5
    const short* wb1 = wsw + W1BASE + ((wv * 32) * 64 + lane) * 8;  // wv*4*8
#define DW0(g,ks) const bs8 w0_##g##_##ks = *(const bs8*)(wb0 + ((g)*5+(ks))*512);
#define DW1(g,ks) const bs8 w1_##g##_##ks = *(const bs8*)(wb1 + ((g)*8+(ks))*512);
    DW0(0,0) DW0(0,1) DW0(0,2) DW0(0,3) DW0(0,4)
    DW0(1,0) DW0(1,1) DW0(1,2) DW0(1,3) DW0(1,4)
    DW0(2,0) DW0(2,1) DW0(2,2) DW0(2,3) DW0(2,4)
    DW0(3,0) DW0(3,1) DW0(3,2) DW0(3,3) DW0(3,4)
    DW1(0,0) DW1(0,1) DW1(0,2) DW1(0,3)
    DW1(1,0) DW1(1,1) DW1(1,2) DW1(1,3)
    DW1(2,0) DW1(2,1) DW1(2,2) DW1(2,3)
    DW1(3,0) DW1(3,1) DW1(3,2) DW1(3,3)

    const float b1_0 = bih1[0 * HID + u] + bhh1[0 * HID + u];
    const float b1_1 = bih1[1 * HID + u] + bhh1[1 * HID + u];
    const float b1_2 = bih1[2 * HID + u] + bhh1[2 * HID + u];
    const float b1_3 = bih1[3 * HID + u] + bhh1[3 * HID + u];

    // ---- LDS init: zeros + constant-1 bias column + L1 ks4-7 weight tiles ----
    for (int idx = tid; idx < 2 * BC * X0STRIDE; idx += 512) ((short*)xh0)[idx] = 0;
    for (int idx = tid; idx < 2 * BC * X1STRIDE; idx += 512) ((short*)xh1)[idx] = 0;
#pragma unroll
    for (int f = 0; f < 16; ++f) {
        int ksm4 = f >> 2, g = f & 3;
        *(bs8*)&wlds[wv][ksm4][g][lane][0] =
            *(const bs8*)(wsw + W1BASE +
                (((wv * 4 + g) * 8 + (ksm4 + 4)) * 64 + lane) * 8);
    }
    __syncthreads();
    if (tid < 2 * BC) xh0[tid >> 4][tid & 15][INS] = (short)0x3f80;  // 1.0 bf16

    // ---- x(t) staging: one float per thread, prefetched one step ahead ----
    const bool xldr = (tid < BC * INS);          // 224 threads
    const int  xm = tid / INS;
    const int  xi = tid - xm * INS;
    const float* xp = xldr ? (x + ((size_t)(b0 + xm) * SEQ) * INS + xi) : x;
    float xv = xldr ? xp[0] : 0.f;

    float c0_0 = 0.f, c0_1 = 0.f, c0_2 = 0.f, c0_3 = 0.f;
    float c1_0 = 0.f, c1_1 = 0.f, c1_2 = 0.f, c1_3 = 0.f;
    const int aoff = quad * 8;

    // ---- MFMA macros; AF passed explicitly (af temps shared L1<->L0) ----
#define L1KR(ks, AF) { \
        acc1_0 = __builtin_amdgcn_mfma_f32_16x16x32_bf16(AF, w1_0_##ks, acc1_0, 0,0,0); \
        acc1_1 = __builtin_amdgcn_mfma_f32_16x16x32_bf16(AF, w1_1_##ks, acc1_1, 0,0,0); \
        acc1_2 = __builtin_amdgcn_mfma_f32_16x16x32_bf16(AF, w1_2_##ks, acc1_2, 0,0,0); \
        acc1_3 = __builtin_amdgcn_mfma_f32_16x16x32_bf16(AF, w1_3_##ks, acc1_3, 0,0,0); }
#define L1KL(ks, AF) { \
        const bs8 u0 = *(const bs8*)&wlds[wv][(ks)-4][0][lane][0]; \
        const bs8 u1 = *(const bs8*)&wlds[wv][(ks)-4][1][lane][0]; \
        const bs8 u2 = *(const bs8*)&wlds[wv][(ks)-4][2][lane][0]; \
        const bs8 u3 = *(const bs8*)&wlds[wv][(ks)-4][3][lane][0]; \
        acc1_0 = __builtin_amdgcn_mfma_f32_16x16x32_bf16(AF, u0, acc1_0, 0,0,0); \
        acc1_1 = __builtin_amdgcn_mfma_f32_16x16x32_bf16(AF, u1, acc1_1, 0,0,0); \
        acc1_2 = __builtin_amdgcn_mfma_f32_16x16x32_bf16(AF, u2, acc1_2, 0,0,0); \
        acc1_3 = __builtin_amdgcn_mfma_f32_16x16x32_bf16(AF, u3, acc1_3, 0,0,0); }
#define L0K(ks, AF) { \
        acc0_0 = __builtin_amdgcn_mfma_f32_16x16x32_bf16(AF, w0_0_##ks, acc0_0, 0,0,0); \
        acc0_1 = __builtin_amdgcn_mfma_f32_16x16x32_bf16(AF, w0_1_##ks, acc0_1, 0,0,0); \
        acc0_2 = __builtin_amdgcn_mfma_f32_16x16x32_bf16(AF, w0_2_##ks, acc0_2, 0,0,0); \
        acc0_3 = __builtin_amdgcn_mfma_f32_16x16x32_bf16(AF, w0_3_##ks, acc0_3, 0,0,0); }

    // ---- merged-denominator LSTM cell: 5 exp2 + 2 rcp per row ----
    // i=1/Di, f=1/Df, g=(1-eg)/Dg, o=1/Do, tanh(c')=(1-ec)/Dc
#define CELLM(A0, A1, A2, A3, cvar, r, ROW, COLOFF) { \
        float ei = __builtin_amdgcn_exp2f(A0[r] * -1.44269504f); \
        float ef = __builtin_amdgcn_exp2f(A1[r] * -1.44269504f); \
        float eg = __builtin_amdgcn_exp2f(A2[r] * -2.88539008f); \
        float eo = __builtin_amdgcn_exp2f(A3[r] * -1.44269504f); \
        float Di = 1.f + ei, Df = 1.f + ef, Dg = 1.f + eg, Do = 1.f + eo; \
        float rP = __builtin_amdgcn_rcpf(Df * Di * Dg); \
        float num = __builtin_fmaf(cvar * Di, Dg, (1.f - eg) * Df); \
        cvar = num * rP; \
        float ec = __builtin_amdgcn_exp2f(cvar * -2.88539008f); \
        float rQ = __builtin_amdgcn_rcpf((1.f + ec) * Do); \
        float h = (1.f - ec) * rQ; \
        xh1[ROW][quad * 4 + (r)][(COLOFF) + u] = f2bf(h); }

#define CELL0(r) CELLM(acc0_0, acc0_1, acc0_2, acc0_3, c0_##r, r, q, 0)
#define CELL1(r) CELLM(acc1_0, acc1_1, acc1_2, acc1_3, c1_##r, r, q, HID)

    // ---- prologue t=0: layer 0 only (h0(-1)=0 from zero-init) ----
    {
        const int p = 0, q = 1;
        if (xldr) xh0[p][xm][xi] = f2bf(xv);
        float xnext = xldr ? xp[INS] : 0.f;
        __syncthreads();
        const bs8 afx = *(const bs8*)&xh0[p][col][aoff];
        const bs8 af0 = *(const bs8*)&xh1[p][col][0 * 32 + aoff];
        const bs8 af1 = *(const bs8*)&xh1[p][col][1 * 32 + aoff];
        const bs8 af2 = *(const bs8*)&xh1[p][col][2 * 32 + aoff];
        const bs8 af3 = *(const bs8*)&xh1[p][col][3 * 32 + aoff];
        f4 acc0_0 = {0.f,0.f,0.f,0.f}, acc0_1 = {0.f,0.f,0.f,0.f};
        f4 acc0_2 = {0.f,0.f,0.f,0.f}, acc0_3 = {0.f,0.f,0.f,0.f};
        L0K(0, afx) L0K(1, af0) L0K(2, af1) L0K(3, af2) L0K(4, af3)
        CELL0(0) CELL0(1) CELL0(2) CELL0(3)
        xv = xnext;
    }

    // ---- steady state: iter t does L1/CELL1 for t-1 and L0/CELL0 for t ----
    for (int t = 1; t < SEQ; ++t) {
        const int p = t & 1, q = p ^ 1;
        if (xldr) xh0[p][xm][xi] = f2bf(xv);
        float xnext = (xldr && (t + 1 < SEQ)) ? xp[(t + 1) * INS] : 0.f;
        __syncthreads();  // x(t), h0(t-1), h1(t-2) all visible in parity p

        // A-row burst: 9 ds_read_b128, loaded once, shared by L1 and L0
        const bs8 afx = *(const bs8*)&xh0[p][col][aoff];
        const bs8 af0 = *(const bs8*)&xh1[p][col][0 * 32 + aoff];
        const bs8 af1 = *(const bs8*)&xh1[p][col][1 * 32 + aoff];
        const bs8 af2 = *(const bs8*)&xh1[p][col][2 * 32 + aoff];
        const bs8 af3 = *(const bs8*)&xh1[p][col][3 * 32 + aoff];
        const bs8 af4 = *(const bs8*)&xh1[p][col][4 * 32 + aoff];
        const bs8 af5 = *(const bs8*)&xh1[p][col][5 * 32 + aoff];
        const bs8 af6 = *(const bs8*)&xh1[p][col][6 * 32 + aoff];
        const bs8 af7 = *(const bs8*)&xh1[p][col][7 * 32 + aoff];

        f4 acc1_0 = {b1_0, b1_0, b1_0, b1_0};
        f4 acc1_1 = {b1_1, b1_1, b1_1, b1_1};
        f4 acc1_2 = {b1_2, b1_2, b1_2, b1_2};
        f4 acc1_3 = {b1_3, b1_3, b1_3, b1_3};
        L1KR(0, af0) L1KR(1, af1) L1KR(2, af2) L1KR(3, af3)
        L1KL(4, af4) L1KL(5, af5) L1KL(6, af6) L1KL(7, af7)

        f4 acc0_0 = {0.f,0.f,0.f,0.f}, acc0_1 = {0.f,0.f,0.f,0.f};
        f4 acc0_2 = {0.f,0.f,0.f,0.f}, acc0_3 = {0.f,0.f,0.f,0.f};
        // interleave: matrix pipe (L0) and trans pipe (CELL1) concurrently
        L0K(0, afx) CELL1(0)
        L0K(1, af0) CELL1(1)
        L0K(2, af1) CELL1(2)
        L0K(3, af2) CELL1(3)
        L0K(4, af3)
        CELL0(0) CELL0(1) CELL0(2) CELL0(3)

        xv = xnext;
    }

    // ---- epilogue: L1/CELL1 for t = SEQ-1 (SEQ even -> parity 0) ----
    {
        const int p = 0, q = 1;
        __syncthreads();
        const bs8 af0 = *(const bs8*)&xh1[p][col][0 * 32 + aoff];
        const bs8 af1 = *(const bs8*)&xh1[p][col][1 * 32 + aoff];
        const bs8 af2 = *(const bs8*)&xh1[p][col][2 * 32 + aoff];
        const bs8 af3 = *(const bs8*)&xh1[p][col][3 * 32 + aoff];
        const bs8 af4 = *(const bs8*)&xh1[p][col][4 * 32 + aoff];
        const bs8 af5 = *(const bs8*)&xh1[p][col][5 * 32 + aoff];
        const bs8 af6 = *(const bs8*)&xh1[p][col][6 * 32 + aoff];
        const bs8 af7 = *(const bs8*)&xh1[p][col][7 * 32 + aoff];
        f4 acc1_0 = {b1_0, b1_0, b1_0, b1_0};
        f4 acc1_1 = {b1_1, b1_1, b1_1, b1_1};
        f4 acc1_2 = {b1_2, b1_2, b1_2, b1_2};
        f4 acc1_3 = {b1_3, b1_3, b1_3, b1_3};
        L1KR(0, af0) L1KR(1, af1) L1KR(2, af2) L1KR(3, af3)
        L1KL(4, af4) L1KL(5, af5) L1KL(6, af6) L1KL(7, af7)
        CELL1(0) CELL1(1) CELL1(2) CELL1(3)
    }
    __syncthreads();

    // ---- final FC (128 -> 1) + sigmoid; h1(SEQ-1) lives in xh1[1][.][HID+..] ----
    if (tid < BC) {
        float s = bfc[0];
#pragma unroll 8
        for (int k2 = 0; k2 < HID; ++k2)
            s += bf2f(xh1[1][tid][HID + k2]) * Wfc[k2];
        out[b0 + tid] = sigm(s);
    }
}

extern "C" void kernel_launch(void* const* d_in, const int* in_sizes, int n_in,
                              void* d_out, int out_size, void* d_ws, size_t ws_size,
                              hipStream_t stream) {
    const float* x    = (const float*)d_in[0];
    const float* Wih0 = (const float*)d_in[1];
    const float* Whh0 = (const float*)d_in[2];
    const float* bih0 = (const float*)d_in[3];
    const float* bhh0 = (const float*)d_in[4];
    const float* Wih1 = (const float*)d_in[5];
    const float* Whh1 = (const float*)d_in[6];
    const float* bih1 = (const float*)d_in[7];
    const float* bhh1 = (const float*)d_in[8];
    const float* Wfc  = (const float*)d_in[9];
    const float* bfc  = (const float*)d_in[10];
    float* out = (float*)d_out;
    short* wsw = (short*)d_ws;   // 426 KB of bf16 fragment-ordered weights

    int nfrag = NFRAG0 + NFRAG1;
    lstm_prep<<<(nfrag + 255) / 256, 256, 0, stream>>>(Wih0, Whh0, bih0, bhh0,
                                                       Wih1, Whh1, wsw);
    dim3 grid(2048 / BC);   // 128 blocks, 1 per CU
    dim3 block(512);        // 8 waves; each wave owns 16 hidden units
    lstm_fused<<<grid, block, 0, stream>>>(x, Wfc, bfc, bih1, bhh1, wsw, out);
}